// Round 6
// baseline (1364.220 us; speedup 1.0000x reference)
//
#include <hip/hip_runtime.h>

typedef unsigned short ushort_t;
typedef unsigned int uint_t;
typedef __attribute__((ext_vector_type(8))) short short8;
typedef __attribute__((ext_vector_type(4))) float f32x4;
typedef __attribute__((ext_vector_type(4))) uint_t uint4a;
typedef __attribute__((ext_vector_type(2))) uint_t uint2a;

#define Tn 256
#define Bn 64
#define Hn 512
#define En 256
#define G4 2048
#define Nt 6

// bf16 NaN sentinel: f2bf of any finite float can yield at most 0x7F80 (inf);
// 0x7FC0 (quiet NaN) is unreachable => safe "not yet written" marker.
#define SENT 0x7FC07FC0u

// ---------- helpers ----------
__device__ inline ushort_t f2bf(float f) {
    uint_t u = __float_as_uint(f);
    uint_t r = u + 0x7FFFu + ((u >> 16) & 1u);
    return (ushort_t)(r >> 16);
}
__device__ inline float bf2f(ushort_t h) { return __uint_as_float(((uint_t)h) << 16); }
__device__ inline float sigm(float x) { return 1.f / (1.f + __expf(-x)); }
__device__ inline float tanh_(float x) { return 2.f / (1.f + __expf(-2.f * x)) - 1.f; }

// All steady-loop VMEM is inline asm: the wave's vmcnt ledger is fully ours.
// Counted waits (vmcnt(6)) interleave two chains without draining each
// other's in-flight ops; vmcnt(0) only on the rare retry path.
// sc1 = device scope (IF$); plain = L2-cached (x, mask).
// !! asm loads invisible to compiler waitcnt pass: wait + sched_barrier(0)
// before any consumer (incl. register-only sentinel compares).
__device__ inline uint4a gload16_sc1(const void* p) {
    uint4a r;
    asm volatile("global_load_dwordx4 %0, %1, off sc1" : "=v"(r) : "v"(p) : "memory");
    return r;
}
__device__ inline uint4a gload16_pl(const void* p) {
    uint4a r;
    asm volatile("global_load_dwordx4 %0, %1, off" : "=v"(r) : "v"(p) : "memory");
    return r;
}
__device__ inline int gload4_pl(const void* p) {
    int r;
    asm volatile("global_load_dword %0, %1, off" : "=v"(r) : "v"(p) : "memory");
    return r;
}
__device__ inline void gstore4_sc1(void* p, uint_t v) {
    asm volatile("global_store_dword %0, %1, off sc1" :: "v"(p), "v"(v) : "memory");
}
__device__ inline void vm_drain() { asm volatile("s_waitcnt vmcnt(0)" ::: "memory"); }

// ---------- ws layout (bytes) ----------
// hbuf: [dir][257 slots][64 batch][512] bf16. Slot s = h-state after s steps
// (slot 0 = h0). Write-once per launch => data-is-the-flag synchronization.
#define OFF_XBF    0u               // 16384*256 bf16        = 8,388,608
#define OFF_WIH    8388608u         // 2*2048*256 bf16       = 2,097,152
#define OFF_WHH    10485760u        // 2*2048*512 bf16       = 4,194,304
#define OFF_HBUF   14680064u        // 2*257*64*512 bf16     = 33,685,504 (end 48,365,568)
#define OFF_EMIS   8388608u         // overlays WIH (dead after lstm; prep rewrites each call)

#define SLOT_U     32768u           // ushorts per slot (64*512)
#define DIR_U      8421376u         // ushorts per dir (257*32768)

// ---------- kernel 1: prep ----------
__global__ void prep_kernel(const int* __restrict__ sent, const float* __restrict__ embed,
                            const float* __restrict__ Wihf, const float* __restrict__ Whhf,
                            const float* __restrict__ Wihb, const float* __restrict__ Whhb,
                            const float* __restrict__ h0, float* __restrict__ out,
                            ushort_t* __restrict__ x_bf, ushort_t* __restrict__ Wih_bf,
                            ushort_t* __restrict__ Whh_bf, ushort_t* __restrict__ hbuf) {
    long i = (long)blockIdx.x * 256 + threadIdx.x;
    const long nA = 524288, nB = 262144, nC = 1048576, nD = 32768, nE = 1048576;
    if (i < nA) {  // Whh cast: [dir][2048][512], 4 elems
        long e4 = i << 2;
        long d = e4 >> 20, r = e4 & 1048575;
        const float* W = d ? Whhb : Whhf;
        float4 v = *(const float4*)(W + r);
        uint2a pv;
        pv.x = (uint_t)f2bf(v.x) | ((uint_t)f2bf(v.y) << 16);
        pv.y = (uint_t)f2bf(v.z) | ((uint_t)f2bf(v.w) << 16);
        *(uint2a*)(Whh_bf + e4) = pv;
        return;
    }
    i -= nA;
    if (i < nB) {  // Wih cast: [dir][2048][256], 4 elems
        long e4 = i << 2;
        long d = e4 >> 19, r = e4 & 524287;
        const float* W = d ? Wihb : Wihf;
        float4 v = *(const float4*)(W + r);
        uint2a pv;
        pv.x = (uint_t)f2bf(v.x) | ((uint_t)f2bf(v.y) << 16);
        pv.y = (uint_t)f2bf(v.z) | ((uint_t)f2bf(v.w) << 16);
        *(uint2a*)(Wih_bf + (d << 19) + r) = pv;
        return;
    }
    i -= nB;
    if (i < nC) {  // x gather: row = t*B+b, 4 elems within one embed row
        long e4 = i << 2;
        long row = e4 >> 8, e = e4 & 255;
        int tok = sent[row];
        float4 v = *(const float4*)(embed + (size_t)tok * 256 + e);
        uint2a pv;
        pv.x = (uint_t)f2bf(v.x) | ((uint_t)f2bf(v.y) << 16);
        pv.y = (uint_t)f2bf(v.z) | ((uint_t)f2bf(v.w) << 16);
        *(uint2a*)(x_bf + e4) = pv;
        return;
    }
    i -= nC;
    if (i < nD) {  // h0 -> hbuf[dir][slot 0][b][jw*2..+1], one bf16 pair (sc1)
        long dir = i >> 14, rem = i & 16383;
        long b = rem >> 8, jw = rem & 255;
        const float* hp = h0 + (size_t)dir * Bn * Hn + (size_t)b * Hn + jw * 2;
        gstore4_sc1(hbuf + (size_t)dir * DIR_U + b * 512 + jw * 2,
                    (uint_t)f2bf(hp[0]) | ((uint_t)f2bf(hp[1]) << 16));
        return;
    }
    i -= nD;
    if (i < nE) {  // sentinel fill: slots 1..256 both dirs, 32B/thread.
        long dir = i >> 19, rem = i & 524287;
        ushort_t* p = hbuf + (size_t)dir * DIR_U + SLOT_U + (size_t)rem * 16;
        uint4a s; s.x = SENT; s.y = SENT; s.z = SENT; s.w = SENT;
        *(uint4a*)p = s;
        *(uint4a*)(p + 8) = s;
        return;
    }
    if (i == nE) { out[0] = 0.f; }
}

// ---------- kernel 2: persistent fused BiLSTM, 2 chains per WG ----------
// 64 WGs: dir(2) x gate-slice(32). 256 threads. Each WG runs BOTH
// batch-half chains P(bh=0), Q(bh=1) of its dir (weights shared). Counted
// vmcnt(6) interleave: each chain's h-loads are issued mid-partner-block
// and fly through the partner's wait+compute — per-chain period drops from
// RTT+c to (RTT+c)/2. Data-is-the-flag sentinel protocol per chain;
// bounded retry => wrong-answer-not-hang on any protocol bug.
__global__ void __launch_bounds__(256, 1) lstm_kernel(
    const ushort_t* __restrict__ x_bf, const ushort_t* __restrict__ Wih_bf,
    const ushort_t* __restrict__ Whh_bf, const float* __restrict__ biasf,
    const float* __restrict__ biasb, const float* __restrict__ c0,
    const int* __restrict__ mask, ushort_t* __restrict__ hbuf,
    float* __restrict__ scratch) {

    __shared__ __align__(16) ushort_t x_sP[2][32 * 264];
    __shared__ __align__(16) ushort_t x_sQ[2][32 * 264];
    __shared__ __align__(16) ushort_t h_s[32 * 520];     // shared by P/Q (barrier-separated)
    __shared__ __align__(16) float gates_s[64 * 35];

    const int tid = threadIdx.x;
    const int wid = blockIdx.x;
    const int dir = wid >> 5;
    const int gs  = wid & 31;
    const int j0  = gs * 16;
    (void)gs;

    const int lane = tid & 63;
    const int wv = tid >> 6;            // wave = gate type (i,f,g,o)
    const int qo = (lane >> 4) * 8;     // k-chunk offset in fragment
    const int ml = lane & 15;

    // persistent B fragments (shared by both chains: same dir, same rows)
    const int grow = wv * 512 + j0 + ml;
    short8 bxf[8], bhf[16];
    {
        const ushort_t* wr = Wih_bf + (size_t)dir * G4 * En + (size_t)grow * En + qo;
        #pragma unroll
        for (int ks = 0; ks < 8; ++ks) bxf[ks] = *(const short8*)(wr + ks * 32);
        const ushort_t* wr2 = Whh_bf + (size_t)dir * G4 * Hn + (size_t)grow * Hn + qo;
        #pragma unroll
        for (int ks = 0; ks < 16; ++ks) bhf[ks] = *(const short8*)(wr2 + ks * 32);
    }
    const float bv = (dir ? biasb : biasf)[grow];

    const int jp = (tid & 7) * 2;
    const int bl = tid >> 3;
    float cregP[2], cregQ[2];
    #pragma unroll
    for (int r = 0; r < 2; ++r) {
        cregP[r] = c0[(size_t)dir * Bn * Hn + (size_t)bl * Hn + j0 + jp + r];
        cregQ[r] = c0[(size_t)dir * Bn * Hn + (size_t)(32 + bl) * Hn + j0 + jp + r];
    }

    const ushort_t* xbP = x_bf;
    const ushort_t* xbQ = x_bf + (size_t)32 * En;
    ushort_t* paneP = hbuf + (size_t)dir * DIR_U;
    ushort_t* paneQ = paneP + (size_t)32 * 512;

    // per-chain async state (live across partner blocks)
    uint4a hregP[8], hregQ[8];
    uint4a xregP[4], xregQ[4];
    int mnxP = 0, mnxQ = 0, mvP = 0, mvQ = 0;

    // prologue: stage x(t0) both chains (compiler loads, drained below)
    {
        const int t0 = dir ? (Tn - 1) : 0;
        const uint4* gP = (const uint4*)(xbP + (size_t)t0 * Bn * En);
        const uint4* gQ = (const uint4*)(xbQ + (size_t)t0 * Bn * En);
        uint4 xp[4], xq[4];
        #pragma unroll
        for (int k = 0; k < 4; ++k) { xp[k] = gP[tid + k * 256]; xq[k] = gQ[tid + k * 256]; }
        #pragma unroll
        for (int k = 0; k < 4; ++k) {
            int c16 = tid + k * 256;
            *(uint4*)&x_sP[0][(c16 >> 5) * 264 + (c16 & 31) * 8] = xp[k];
            *(uint4*)&x_sQ[0][(c16 >> 5) * 264 + (c16 & 31) * 8] = xq[k];
        }
    }
    __syncthreads();
    vm_drain();   // ledger empty before counted-wait regime

    // prologue asm issues — order defines the vmcnt(6) arithmetic:
    // [P-xm(5), P-h(8), Q-xm(5), dummy(1)] -> at P-validate(0) the newest 6
    // = Q-xm+dummy, so vmcnt(6) retires P-h and P-xm.
    {
        const int t0 = dir ? (Tn - 1) : 0;
        const int t1i = (Tn > 1) ? 1 : 0;
        const int t1 = dir ? (Tn - 1 - t1i) : t1i;
        const ushort_t* g = xbP + (size_t)t1 * Bn * En;
        #pragma unroll
        for (int k = 0; k < 4; ++k)
            xregP[k] = gload16_pl(g + (size_t)(tid + k * 256) * 8);
        mnxP = gload4_pl(&mask[t0 * Bn + bl]);
        #pragma unroll
        for (int k = 0; k < 8; ++k)
            hregP[k] = gload16_sc1(paneP + (size_t)(tid + k * 256) * 8);
        const ushort_t* g2 = xbQ + (size_t)t1 * Bn * En;
        #pragma unroll
        for (int k = 0; k < 4; ++k)
            xregQ[k] = gload16_pl(g2 + (size_t)(tid + k * 256) * 8);
        mnxQ = gload4_pl(&mask[t0 * Bn + 32 + bl]);
        gstore4_sc1(scratch + (size_t)wid * 256 + tid, 0u);   // dummy: pads ledger to 6
    }

// One chain block. Entering: previous block ended with __syncthreads().
//  vmcnt(6) -> validate h(s) (bounded retry w/ full drain) -> stage h_s +
//  x_s[nxt] -> bar -> issue partner h (slot slotO) -> x-MFMA + h-MFMA +
//  gates -> bar -> update + sc1 h-store(slot s+1) -> issue own x(t_{s+2}),
//  mask(t_{s+1}) -> bar.
#define SBLK(S, O, slotO, BGOFF)                                               \
    {                                                                          \
        asm volatile("s_waitcnt vmcnt(6)" ::: "memory");                       \
        __builtin_amdgcn_sched_barrier(0);                                     \
        mv##S = mnx##S;                                                        \
        {                                                                      \
            const ushort_t* hp0 = pane##S + (size_t)s * SLOT_U;                \
            bool ok = true;                                                    \
            _Pragma("unroll")                                                  \
            for (int k = 0; k < 8; ++k)                                        \
                _Pragma("unroll")                                              \
                for (int w = 0; w < 4; ++w) ok &= (hreg##S[k][w] != SENT);     \
            int guard = 65536;                                                 \
            while (!ok && --guard) {                                           \
                __builtin_amdgcn_s_sleep(2);                                   \
                _Pragma("unroll")                                              \
                for (int k = 0; k < 8; ++k)                                    \
                    hreg##S[k] = gload16_sc1(hp0 + (size_t)(tid + k * 256) * 8); \
                vm_drain();                                                    \
                __builtin_amdgcn_sched_barrier(0);                             \
                ok = true;                                                     \
                _Pragma("unroll")                                              \
                for (int k = 0; k < 8; ++k)                                    \
                    _Pragma("unroll")                                          \
                    for (int w = 0; w < 4; ++w) ok &= (hreg##S[k][w] != SENT); \
            }                                                                  \
        }                                                                      \
        _Pragma("unroll")                                                      \
        for (int k = 0; k < 8; ++k) {                                          \
            int c16 = tid + k * 256;                                           \
            *(uint4a*)&h_s[(c16 >> 6) * 520 + (c16 & 63) * 8] = hreg##S[k];    \
        }                                                                      \
        _Pragma("unroll")                                                      \
        for (int k = 0; k < 4; ++k) {                                          \
            int c16 = tid + k * 256;                                           \
            *(uint4a*)&x_s##S[nxt][(c16 >> 5) * 264 + (c16 & 31) * 8] = xreg##S[k]; \
        }                                                                      \
        __syncthreads();                                                       \
        {   /* issue partner h(slotO): flies through the rest of this block */ \
            const ushort_t* po = pane##O + (size_t)(slotO) * SLOT_U;           \
            _Pragma("unroll")                                                  \
            for (int k = 0; k < 8; ++k)                                        \
                hreg##O[k] = gload16_sc1(po + (size_t)(tid + k * 256) * 8);    \
        }                                                                      \
        {                                                                      \
            f32x4 acc0, acc1;                                                  \
            _Pragma("unroll")                                                  \
            for (int r = 0; r < 4; ++r) { acc0[r] = bv; acc1[r] = bv; }        \
            const ushort_t* xr0 = &x_s##S[cur][ml * 264 + qo];                 \
            const ushort_t* xr1 = &x_s##S[cur][(16 + ml) * 264 + qo];          \
            _Pragma("unroll")                                                  \
            for (int ks = 0; ks < 8; ++ks) {                                   \
                short8 a0 = *(const short8*)(xr0 + ks * 32);                   \
                short8 a1 = *(const short8*)(xr1 + ks * 32);                   \
                acc0 = __builtin_amdgcn_mfma_f32_16x16x32_bf16(a0, bxf[ks], acc0, 0, 0, 0); \
                acc1 = __builtin_amdgcn_mfma_f32_16x16x32_bf16(a1, bxf[ks], acc1, 0, 0, 0); \
            }                                                                  \
            const ushort_t* hr0 = &h_s[ml * 520 + qo];                         \
            const ushort_t* hr1 = &h_s[(16 + ml) * 520 + qo];                  \
            _Pragma("unroll")                                                  \
            for (int ks = 0; ks < 16; ++ks) {                                  \
                short8 a0 = *(const short8*)(hr0 + ks * 32);                   \
                short8 a1 = *(const short8*)(hr1 + ks * 32);                   \
                acc0 = __builtin_amdgcn_mfma_f32_16x16x32_bf16(a0, bhf[ks], acc0, 0, 0, 0); \
                acc1 = __builtin_amdgcn_mfma_f32_16x16x32_bf16(a1, bhf[ks], acc1, 0, 0, 0); \
            }                                                                  \
            int nl = wv * 16 + ml;                                             \
            int br = (lane >> 4) * 4;                                          \
            _Pragma("unroll")                                                  \
            for (int r = 0; r < 4; ++r) {                                      \
                gates_s[nl * 35 + br + r]      = acc0[r];                      \
                gates_s[nl * 35 + 16 + br + r] = acc1[r];                      \
            }                                                                  \
        }                                                                      \
        __syncthreads();                                                       \
        {                                                                      \
            ushort_t hu[2];                                                    \
            _Pragma("unroll")                                                  \
            for (int r = 0; r < 2; ++r) {                                      \
                int j = jp + r;                                                \
                float iv  = gates_s[j * 35 + bl];                              \
                float fvv = gates_s[(16 + j) * 35 + bl];                       \
                float gv  = gates_s[(32 + j) * 35 + bl];                       \
                float ov  = gates_s[(48 + j) * 35 + bl];                       \
                float cn = sigm(fvv) * creg##S[r] + sigm(iv) * tanh_(gv);      \
                float hn = sigm(ov) * tanh_(cn);                               \
                float hp = bf2f(h_s[bl * 520 + j0 + j]);                       \
                float h2;                                                      \
                if (mv##S) { creg##S[r] = cn; h2 = hn; }                       \
                else       { h2 = hp; }                                        \
                hu[r] = f2bf(h2);                                              \
            }                                                                  \
            gstore4_sc1(pane##S + (size_t)(s + 1) * SLOT_U + (size_t)bl * 512 + j0 + jp, \
                        (uint_t)hu[0] | ((uint_t)hu[1] << 16));                \
        }                                                                      \
        {   /* issue own x(t_{s+2}) + mask(t_{s+1}): 5 ops */                  \
            const ushort_t* g = xb##S + (size_t)tx * Bn * En;                  \
            _Pragma("unroll")                                                  \
            for (int k = 0; k < 4; ++k)                                        \
                xreg##S[k] = gload16_pl(g + (size_t)(tid + k * 256) * 8);      \
            mnx##S = gload4_pl(&mask[tm * Bn + (BGOFF) + bl]);                 \
        }                                                                      \
        __syncthreads();                                                       \
    }

    for (int s = 0; s < Tn; ++s) {
        const int sm = (s + 1 < Tn) ? s + 1 : Tn - 1;
        const int sx = (s + 2 < Tn) ? s + 2 : Tn - 1;
        const int tm = dir ? (Tn - 1 - sm) : sm;
        const int tx = dir ? (Tn - 1 - sx) : sx;
        const int cur = s & 1, nxt = cur ^ 1;

        SBLK(P, Q, s, 0)        // P step s; issues Q-h(s) mid-block
        SBLK(Q, P, s + 1, 32)   // Q step s; issues P-h(s+1) mid-block
    }
#undef SBLK
}

// ---------- kernel 3: emission projection (wave per row) ----------
// h_masked[t] = mask(t) ? hbuf[dir0][t+1] / hbuf[dir1][256-t] : 0.
__global__ void emis_kernel(const ushort_t* __restrict__ hbuf, const int* __restrict__ mask,
                            const float* __restrict__ Wout, const float* __restrict__ bout,
                            float* __restrict__ emis) {
    int row = blockIdx.x * 4 + (threadIdx.x >> 6);   // t*64 + b
    int lane = threadIdx.x & 63;
    int t = row >> 6, b = row & 63;
    float mf = mask[row] ? 1.f : 0.f;
    size_t slot = (lane < 32) ? (size_t)(t + 1) * SLOT_U
                              : (size_t)DIR_U + (size_t)(Tn - t) * SLOT_U;
    const ushort_t* hr = hbuf + slot + (size_t)b * 512 + (lane & 31) * 16;
    short8 h0v = *(const short8*)(hr);
    short8 h1v = *(const short8*)(hr + 8);
    float hv[16];
    #pragma unroll
    for (int j = 0; j < 8; ++j) {
        hv[j]     = bf2f((ushort_t)h0v[j]);
        hv[j + 8] = bf2f((ushort_t)h1v[j]);
    }
    float acc[6];
    #pragma unroll
    for (int n = 0; n < Nt; ++n) {
        const float* w = Wout + n * 1024 + lane * 16;   // lane*16 == concat index
        float a = 0.f;
        #pragma unroll
        for (int j = 0; j < 16; ++j) a += hv[j] * w[j];
        acc[n] = a;
    }
    #pragma unroll
    for (int n = 0; n < Nt; ++n) {
        float v = acc[n];
        #pragma unroll
        for (int off = 32; off; off >>= 1) v += __shfl_down(v, off);
        if (lane == 0) emis[row * Nt + n] = v * mf + bout[n];
    }
}

// ---------- kernel 4: CRF LLH (one wave per batch) ----------
__global__ void crf_kernel(const int* __restrict__ tags, const int* __restrict__ mask,
                           const float* __restrict__ emis, const float* __restrict__ trans,
                           const float* __restrict__ startt, const float* __restrict__ endt,
                           float* __restrict__ out) {
    int b = blockIdx.x;
    int lane = threadIdx.x;

    float part = 0.f;
    int mc = 0;
    for (int t = lane; t < Tn; t += 64) {
        int mv = mask[t * Bn + b];
        mc += mv;
        if (t >= 1) {
            int tp = tags[(t - 1) * Bn + b], tc = tags[t * Bn + b];
            part += (trans[tp * Nt + tc] + emis[(t * Bn + b) * Nt + tc]) * (float)mv;
        }
    }
    #pragma unroll
    for (int off = 32; off; off >>= 1) {
        part += __shfl_down(part, off);
        mc += __shfl_down(mc, off);
    }
    float num = 0.f;
    if (lane == 0) {
        int t0g = tags[b];
        num = startt[t0g] + emis[b * Nt + t0g] + part;
        int last = mc - 1;
        num += endt[tags[last * Bn + b]];
    }

    if (lane < Nt) {
        int j = lane;
        float tr[6];
        #pragma unroll
        for (int i = 0; i < Nt; ++i) tr[i] = trans[i * Nt + j];
        float score = startt[j] + emis[b * Nt + j];
        float e_nx = emis[(Bn + b) * Nt + j];
        int   m_nx = mask[Bn + b];
        for (int t = 1; t < Tn; ++t) {
            float e = e_nx;
            int mv = m_nx;
            if (t + 1 < Tn) {
                e_nx = emis[((t + 1) * Bn + b) * Nt + j];
                m_nx = mask[(t + 1) * Bn + b];
            }
            float v[6];
            float mx = -1e30f;
            #pragma unroll
            for (int i = 0; i < Nt; ++i) { v[i] = __shfl(score, i) + tr[i]; mx = fmaxf(mx, v[i]); }
            float sm = 0.f;
            #pragma unroll
            for (int i = 0; i < Nt; ++i) sm += __expf(v[i] - mx);
            float nxtv = mx + __logf(sm) + e;
            score = mv > 0 ? nxtv : score;
        }
        float fvv = score + endt[j];
        float m2 = fvv;
        #pragma unroll
        for (int i = 0; i < Nt; ++i) m2 = fmaxf(m2, __shfl(fvv, i));
        float s2 = 0.f;
        #pragma unroll
        for (int i = 0; i < Nt; ++i) s2 += __expf(__shfl(fvv, i) - m2);
        if (lane == 0) {
            float denom = m2 + __logf(s2);
            atomicAdd(out, num - denom);
        }
    }
}

extern "C" void kernel_launch(void* const* d_in, const int* in_sizes, int n_in,
                              void* d_out, int out_size, void* d_ws, size_t ws_size,
                              hipStream_t stream) {
    (void)in_sizes; (void)n_in; (void)out_size; (void)ws_size;
    const int*   sent  = (const int*)d_in[0];
    const int*   tags  = (const int*)d_in[1];
    const int*   mask  = (const int*)d_in[2];
    const float* h0    = (const float*)d_in[3];
    const float* c0    = (const float*)d_in[4];
    const float* embed = (const float*)d_in[5];
    const float* Wihf  = (const float*)d_in[6];
    const float* Whhf  = (const float*)d_in[7];
    const float* bf_   = (const float*)d_in[8];
    const float* Wihb  = (const float*)d_in[9];
    const float* Whhb  = (const float*)d_in[10];
    const float* bb_   = (const float*)d_in[11];
    const float* Wout  = (const float*)d_in[12];
    const float* bout  = (const float*)d_in[13];
    const float* trans = (const float*)d_in[14];
    const float* stt   = (const float*)d_in[15];
    const float* ent   = (const float*)d_in[16];
    float* out = (float*)d_out;
    char* ws = (char*)d_ws;

    ushort_t* x_bf   = (ushort_t*)(ws + OFF_XBF);
    ushort_t* Wih_bf = (ushort_t*)(ws + OFF_WIH);
    ushort_t* Whh_bf = (ushort_t*)(ws + OFF_WHH);
    ushort_t* hbuf   = (ushort_t*)(ws + OFF_HBUF);
    float*    emis   = (float*)(ws + OFF_EMIS);

    // prep threads: 524288+262144+1048576+32768+1048576+1 = 2,916,353
    prep_kernel<<<11393, 256, 0, stream>>>(sent, embed, Wihf, Whhf, Wihb, Whhb,
                                           h0, out, x_bf, Wih_bf, Whh_bf, hbuf);
    // dummy stores land in the emis region (fully overwritten by emis_kernel)
    lstm_kernel<<<64, 256, 0, stream>>>(x_bf, Wih_bf, Whh_bf, bf_, bb_, c0,
                                        mask, hbuf, emis);
    emis_kernel<<<4096, 256, 0, stream>>>(hbuf, mask, Wout, bout, emis);
    crf_kernel<<<64, 64, 0, stream>>>(tags, mask, emis, trans, stt, ent, out);
}

// Round 8
// 988.304 us; speedup vs baseline: 1.3804x; 1.3804x over previous
//
#include <hip/hip_runtime.h>

typedef unsigned short ushort_t;
typedef unsigned int uint_t;
typedef __attribute__((ext_vector_type(8))) short short8;
typedef __attribute__((ext_vector_type(4))) float f32x4;
typedef __attribute__((ext_vector_type(4))) uint_t uint4a;
typedef __attribute__((ext_vector_type(2))) uint_t uint2a;

#define Tn 256
#define Bn 64
#define Hn 512
#define En 256
#define G4 2048
#define Nt 6

// bf16 NaN sentinel: f2bf of any finite float can yield at most 0x7F80 (inf);
// 0x7FC0 (quiet NaN) is unreachable => safe "not yet written" marker.
#define SENT 0x7FC07FC0u

// ---------- helpers ----------
__device__ inline ushort_t f2bf(float f) {
    uint_t u = __float_as_uint(f);
    uint_t r = u + 0x7FFFu + ((u >> 16) & 1u);
    return (ushort_t)(r >> 16);
}
__device__ inline float bf2f(ushort_t h) { return __uint_as_float(((uint_t)h) << 16); }
__device__ inline float sigm(float x) { return 1.f / (1.f + __expf(-x)); }
__device__ inline float tanh_(float x) { return 2.f / (1.f + __expf(-2.f * x)) - 1.f; }

// All steady-loop VMEM is inline asm: the wave's vmcnt ledger is fully ours
// (no hidden compiler vmcnt(0) drains). sc1 = device scope (IF$ coherence
// point); plain = L2-cached (x, mask). !! asm loads are invisible to the
// compiler's waitcnt pass: wait + sched_barrier(0) before ANY consumer,
// including register-only sentinel compares.
__device__ inline uint4a gload16_sc1(const void* p) {
    uint4a r;
    asm volatile("global_load_dwordx4 %0, %1, off sc1" : "=v"(r) : "v"(p) : "memory");
    return r;
}
__device__ inline uint4a gload16_pl(const void* p) {
    uint4a r;
    asm volatile("global_load_dwordx4 %0, %1, off" : "=v"(r) : "v"(p) : "memory");
    return r;
}
__device__ inline int gload4_pl(const void* p) {
    int r;
    asm volatile("global_load_dword %0, %1, off" : "=v"(r) : "v"(p) : "memory");
    return r;
}
__device__ inline void gstore4_sc1(void* p, uint_t v) {
    asm volatile("global_store_dword %0, %1, off sc1" :: "v"(p), "v"(v) : "memory");
}
__device__ inline void vm_drain() { asm volatile("s_waitcnt vmcnt(0)" ::: "memory"); }

// ---------- ws layout (bytes) ----------
// hbuf: [dir][257 slots][pane(2)][slice(32)][b(32)][16 cols] bf16.
// SLICE-MAJOR: each producer WG's per-step output (slice, 32b x 16cols =
// 1KB) is one contiguous block => full-cache-line single-owner writes, no
// cross-CU partial-line RMW at the coherence point. Slot s = h after s
// steps (slot 0 = h0). Write-once => data-is-the-flag synchronization.
#define OFF_XBF    0u               // 16384*256 bf16        = 8,388,608
#define OFF_WIH    8388608u         // 2*2048*256 bf16       = 2,097,152
#define OFF_WHH    10485760u        // 2*2048*512 bf16       = 4,194,304
#define OFF_HBUF   14680064u        // 2*257*64*512 bf16     = 33,685,504 (end 48,365,568)
#define OFF_EMIS   8388608u         // overlays WIH (dead after lstm; prep rewrites each call)

#define SLOT_U     32768u           // ushorts per slot (2 panes * 16384)
#define PANE_U     16384u           // ushorts per pane (32 slices * 512)
#define DIR_U      8421376u         // ushorts per dir (257*32768)

// ---------- kernel 1: prep ----------
__global__ void prep_kernel(const int* __restrict__ sent, const float* __restrict__ embed,
                            const float* __restrict__ Wihf, const float* __restrict__ Whhf,
                            const float* __restrict__ Wihb, const float* __restrict__ Whhb,
                            const float* __restrict__ h0, float* __restrict__ out,
                            ushort_t* __restrict__ x_bf, ushort_t* __restrict__ Wih_bf,
                            ushort_t* __restrict__ Whh_bf, ushort_t* __restrict__ hbuf) {
    long i = (long)blockIdx.x * 256 + threadIdx.x;
    const long nA = 524288, nB = 262144, nC = 1048576, nD = 32768, nE = 1048576;
    if (i < nA) {  // Whh cast: [dir][2048][512], 4 elems
        long e4 = i << 2;
        long d = e4 >> 20, r = e4 & 1048575;
        const float* W = d ? Whhb : Whhf;
        float4 v = *(const float4*)(W + r);
        uint2a pv;
        pv.x = (uint_t)f2bf(v.x) | ((uint_t)f2bf(v.y) << 16);
        pv.y = (uint_t)f2bf(v.z) | ((uint_t)f2bf(v.w) << 16);
        *(uint2a*)(Whh_bf + e4) = pv;
        return;
    }
    i -= nA;
    if (i < nB) {  // Wih cast: [dir][2048][256], 4 elems
        long e4 = i << 2;
        long d = e4 >> 19, r = e4 & 524287;
        const float* W = d ? Wihb : Wihf;
        float4 v = *(const float4*)(W + r);
        uint2a pv;
        pv.x = (uint_t)f2bf(v.x) | ((uint_t)f2bf(v.y) << 16);
        pv.y = (uint_t)f2bf(v.z) | ((uint_t)f2bf(v.w) << 16);
        *(uint2a*)(Wih_bf + (d << 19) + r) = pv;
        return;
    }
    i -= nB;
    if (i < nC) {  // x gather: row = t*B+b, 4 elems within one embed row
        long e4 = i << 2;
        long row = e4 >> 8, e = e4 & 255;
        int tok = sent[row];
        float4 v = *(const float4*)(embed + (size_t)tok * 256 + e);
        uint2a pv;
        pv.x = (uint_t)f2bf(v.x) | ((uint_t)f2bf(v.y) << 16);
        pv.y = (uint_t)f2bf(v.z) | ((uint_t)f2bf(v.w) << 16);
        *(uint2a*)(x_bf + e4) = pv;
        return;
    }
    i -= nC;
    if (i < nD) {  // h0 -> hbuf[dir][slot0] in SLICE-MAJOR layout, sc1.
                   // (b, cols 2jw..2jw+1): pane=b>>5, slice=jw>>3, c=2(jw&7)
        long dir = i >> 14, rem = i & 16383;
        long b = rem >> 8, jw = rem & 255;
        const float* hp = h0 + (size_t)dir * Bn * Hn + (size_t)b * Hn + jw * 2;
        gstore4_sc1(hbuf + (size_t)dir * DIR_U + (b >> 5) * PANE_U
                         + (jw >> 3) * 512 + (b & 31) * 16 + 2 * (jw & 7),
                    (uint_t)f2bf(hp[0]) | ((uint_t)f2bf(hp[1]) << 16));
        return;
    }
    i -= nD;
    if (i < nE) {  // sentinel fill: slots 1..256 both dirs, 32B/thread
                   // (layout-agnostic uniform fill).
        long dir = i >> 19, rem = i & 524287;
        ushort_t* p = hbuf + (size_t)dir * DIR_U + SLOT_U + (size_t)rem * 16;
        uint4a s; s.x = SENT; s.y = SENT; s.z = SENT; s.w = SENT;
        *(uint4a*)p = s;
        *(uint4a*)(p + 8) = s;
        return;
    }
    if (i == nE) { out[0] = 0.f; }
}

// ---------- kernel 2: persistent fused BiLSTM ----------
// 128 WGs: dir(2) x batch-half(2) x gate-slice(32). 256 threads.
// Data-is-the-flag sentinel protocol, single vm_drain per iteration:
//  A: issue [x(t+1) x4, mask(t+1), h(slot s) x8]   (all inline asm)
//  B: 8 x-part MFMA ksteps (load flight)
//  C: ONE drain (prev h-store is oldest -> acked in parallel); validate
//     per-chunk; PARTIAL retry (reload only stale chunks); stage h_s+x_s
//  D: 16 h-part MFMA ksteps; gates -> LDS (stride 35)
//  E: cell update; ONE coalesced 1KB/WG sc1 h-store block (slice-major)
__global__ void __launch_bounds__(256, 1) lstm_kernel(
    const ushort_t* __restrict__ x_bf, const ushort_t* __restrict__ Wih_bf,
    const ushort_t* __restrict__ Whh_bf, const float* __restrict__ biasf,
    const float* __restrict__ biasb, const float* __restrict__ c0,
    const int* __restrict__ mask, ushort_t* __restrict__ hbuf) {

    __shared__ __align__(16) ushort_t x_s[2][32 * 264];
    __shared__ __align__(16) ushort_t h_s[32 * 520];
    __shared__ __align__(16) float gates_s[64 * 35];

    const int tid = threadIdx.x;
    const int wid = blockIdx.x;
    const int dir = wid >> 6;
    const int bh  = (wid >> 5) & 1;
    const int gs  = wid & 31;
    const int j0  = gs * 16;

    const int lane = tid & 63;
    const int wv = tid >> 6;            // wave = gate type (i,f,g,o)
    const int qo = (lane >> 4) * 8;     // k-chunk offset in fragment
    const int ml = lane & 15;

    // persistent B fragments (W_ih: 8 ksteps, W_hh: 16 ksteps) in VGPRs
    const int grow = wv * 512 + j0 + ml;   // global gate row 0..2047
    short8 bxf[8], bhf[16];
    {
        const ushort_t* wr = Wih_bf + (size_t)dir * G4 * En + (size_t)grow * En + qo;
        #pragma unroll
        for (int ks = 0; ks < 8; ++ks) bxf[ks] = *(const short8*)(wr + ks * 32);
        const ushort_t* wr2 = Whh_bf + (size_t)dir * G4 * Hn + (size_t)grow * Hn + qo;
        #pragma unroll
        for (int ks = 0; ks < 16; ++ks) bhf[ks] = *(const short8*)(wr2 + ks * 32);
    }
    const float bv = (dir ? biasb : biasf)[grow];

    // update-phase mapping: thread -> (2 consecutive j, one batch) => one 4B
    // store; with slice-major layout tid order = contiguous 1KB block.
    const int jp = (tid & 7) * 2;
    const int bl = tid >> 3;
    const int bg = bh * 32 + bl;
    float creg[2];
    #pragma unroll
    for (int r = 0; r < 2; ++r)
        creg[r] = c0[(size_t)dir * Bn * Hn + (size_t)bg * Hn + j0 + jp + r];

    const ushort_t* xbase = x_bf + (size_t)bh * 32 * En;
    const ushort_t* hrd = hbuf + (size_t)dir * DIR_U + (size_t)bh * PANE_U;
    ushort_t*       hwr = hbuf + (size_t)dir * DIR_U + (size_t)bh * PANE_U;

    // prologue (compiler loads, auto-drained): x[t0] -> x_s[0]; mv(t0)
    {
        const int t0 = dir ? (Tn - 1) : 0;
        const uint4* g4 = (const uint4*)(xbase + (size_t)t0 * Bn * En);
        uint4 xp[4];
        #pragma unroll
        for (int k = 0; k < 4; ++k) xp[k] = g4[tid + k * 256];
        #pragma unroll
        for (int k = 0; k < 4; ++k) {
            int c16 = tid + k * 256;
            *(uint4*)&x_s[0][(c16 >> 5) * 264 + (c16 & 31) * 8] = xp[k];
        }
    }
    int mv = mask[(dir ? (Tn - 1) : 0) * Bn + bg];
    __syncthreads();

    for (int s = 0; s < Tn; ++s) {
        const int cur = s & 1, nxt = cur ^ 1;

        // A: asm bundle — x(t of iter s+1), mask(same), h(slot s)
        const int sn = (s + 1 < Tn) ? s + 1 : Tn - 1;
        const int tn = dir ? (Tn - 1 - sn) : sn;
        uint4a xreg[4];
        {
            const ushort_t* g = xbase + (size_t)tn * Bn * En;
            #pragma unroll
            for (int k = 0; k < 4; ++k)
                xreg[k] = gload16_pl(g + (size_t)(tid + k * 256) * 8);
        }
        int mnx = gload4_pl(&mask[tn * Bn + bg]);
        const ushort_t* hp0 = hrd + (size_t)s * SLOT_U;
        uint4a hreg[8];
        #pragma unroll
        for (int k = 0; k < 8; ++k)
            hreg[k] = gload16_sc1(hp0 + (size_t)(tid + k * 256) * 8);

        // B: all 8 x-part MFMA ksteps (load flight)
        f32x4 acc0, acc1;
        #pragma unroll
        for (int r = 0; r < 4; ++r) { acc0[r] = bv; acc1[r] = bv; }
        const ushort_t* xr0 = &x_s[cur][ml * 264 + qo];
        const ushort_t* xr1 = &x_s[cur][(16 + ml) * 264 + qo];
        #pragma unroll
        for (int ks = 0; ks < 8; ++ks) {
            short8 a0 = *(const short8*)(xr0 + ks * 32);
            short8 a1 = *(const short8*)(xr1 + ks * 32);
            acc0 = __builtin_amdgcn_mfma_f32_16x16x32_bf16(a0, bxf[ks], acc0, 0, 0, 0);
            acc1 = __builtin_amdgcn_mfma_f32_16x16x32_bf16(a1, bxf[ks], acc1, 0, 0, 0);
        }

        // C: the ONE drain; per-chunk validate; PARTIAL retry (only stale
        //    chunks reloaded => retry cost ~ one laggard's load, not 32KB).
        //    Bounded guard: wrong-answer-not-hang on any protocol bug.
        vm_drain();
        __builtin_amdgcn_sched_barrier(0);
        {
            uint_t okm = 0;
            #pragma unroll
            for (int k = 0; k < 8; ++k) {
                bool ok = true;
                #pragma unroll
                for (int w = 0; w < 4; ++w) ok &= (hreg[k][w] != SENT);
                okm |= (ok ? 1u : 0u) << k;
            }
            int guard = 65536;
            while (okm != 255u && --guard) {
                __builtin_amdgcn_s_sleep(1);
                #pragma unroll
                for (int k = 0; k < 8; ++k)
                    if (!((okm >> k) & 1))
                        hreg[k] = gload16_sc1(hp0 + (size_t)(tid + k * 256) * 8);
                vm_drain();
                __builtin_amdgcn_sched_barrier(0);
                #pragma unroll
                for (int k = 0; k < 8; ++k) {
                    if (!((okm >> k) & 1)) {
                        bool ok = true;
                        #pragma unroll
                        for (int w = 0; w < 4; ++w) ok &= (hreg[k][w] != SENT);
                        okm |= (ok ? 1u : 0u) << k;
                    }
                }
            }
        }
        // stage h into LDS [b][hcol] from slice-major chunks:
        // chunk c16: slice=c16>>6, w=c16&63 -> b=w>>1, halfcol=(w&1)*8
        #pragma unroll
        for (int k = 0; k < 8; ++k) {
            int c16 = tid + k * 256;
            int slice = c16 >> 6, w = c16 & 63;
            *(uint4a*)&h_s[(w >> 1) * 520 + slice * 16 + (w & 1) * 8] = hreg[k];
        }
        #pragma unroll
        for (int k = 0; k < 4; ++k) {
            int c16 = tid + k * 256;
            *(uint4a*)&x_s[nxt][(c16 >> 5) * 264 + (c16 & 31) * 8] = xreg[k];
        }
        __syncthreads();

        // D: h-part MFMAs; gates to LDS (stride 35: <=2-way bank aliasing)
        {
            const ushort_t* hr0 = &h_s[ml * 520 + qo];
            const ushort_t* hr1 = &h_s[(16 + ml) * 520 + qo];
            #pragma unroll
            for (int ks = 0; ks < 16; ++ks) {
                short8 a0 = *(const short8*)(hr0 + ks * 32);
                short8 a1 = *(const short8*)(hr1 + ks * 32);
                acc0 = __builtin_amdgcn_mfma_f32_16x16x32_bf16(a0, bhf[ks], acc0, 0, 0, 0);
                acc1 = __builtin_amdgcn_mfma_f32_16x16x32_bf16(a1, bhf[ks], acc1, 0, 0, 0);
            }
            int nl = wv * 16 + ml;
            int br = (lane >> 4) * 4;
            #pragma unroll
            for (int r = 0; r < 4; ++r) {
                gates_s[nl * 35 + br + r]      = acc0[r];
                gates_s[nl * 35 + 16 + br + r] = acc1[r];
            }
        }
        __syncthreads();

        // E: cell update; slice-major sc1 h-store: 256 threads x consecutive
        //    4B = one contiguous 1KB block (full-line single-owner writes).
        {
            ushort_t hu[2];
            #pragma unroll
            for (int r = 0; r < 2; ++r) {
                int j = jp + r;
                float iv  = gates_s[j * 35 + bl];
                float fvv = gates_s[(16 + j) * 35 + bl];
                float gv  = gates_s[(32 + j) * 35 + bl];
                float ov  = gates_s[(48 + j) * 35 + bl];
                float cn = sigm(fvv) * creg[r] + sigm(iv) * tanh_(gv);
                float hn = sigm(ov) * tanh_(cn);
                float hp = bf2f(h_s[bl * 520 + j0 + j]);
                float h2;
                if (mv) { creg[r] = cn; h2 = hn; }
                else    { h2 = hp; }
                hu[r] = f2bf(h2);
            }
            gstore4_sc1(hwr + (size_t)(s + 1) * SLOT_U + (size_t)j0 * 32
                            + (size_t)bl * 16 + jp,
                        (uint_t)hu[0] | ((uint_t)hu[1] << 16));
        }
        mv = mnx;
        // protect h_s (read in E) / x_s[nxt] / gates_s for next iteration
        __syncthreads();
    }
}

// ---------- kernel 3: emission projection (wave per row) ----------
// h_masked[t] = mask(t) ? hbuf[dir0][t+1] / hbuf[dir1][256-t] : 0.
// Slice-major: 16 consecutive cols of one batch are contiguous (32B).
__global__ void emis_kernel(const ushort_t* __restrict__ hbuf, const int* __restrict__ mask,
                            const float* __restrict__ Wout, const float* __restrict__ bout,
                            float* __restrict__ emis) {
    int row = blockIdx.x * 4 + (threadIdx.x >> 6);   // t*64 + b
    int lane = threadIdx.x & 63;
    int t = row >> 6, b = row & 63;
    float mf = mask[row] ? 1.f : 0.f;
    size_t slot = (lane < 32) ? (size_t)(t + 1) * SLOT_U
                              : (size_t)DIR_U + (size_t)(Tn - t) * SLOT_U;
    const ushort_t* hr = hbuf + slot + (size_t)(b >> 5) * PANE_U
                       + (size_t)(lane & 31) * 512 + (size_t)(b & 31) * 16;
    short8 h0v = *(const short8*)(hr);
    short8 h1v = *(const short8*)(hr + 8);
    float hv[16];
    #pragma unroll
    for (int j = 0; j < 8; ++j) {
        hv[j]     = bf2f((ushort_t)h0v[j]);
        hv[j + 8] = bf2f((ushort_t)h1v[j]);
    }
    float acc[6];
    #pragma unroll
    for (int n = 0; n < Nt; ++n) {
        const float* w = Wout + n * 1024 + lane * 16;   // lane*16 == concat index
        float a = 0.f;
        #pragma unroll
        for (int j = 0; j < 16; ++j) a += hv[j] * w[j];
        acc[n] = a;
    }
    #pragma unroll
    for (int n = 0; n < Nt; ++n) {
        float v = acc[n];
        #pragma unroll
        for (int off = 32; off; off >>= 1) v += __shfl_down(v, off);
        if (lane == 0) emis[row * Nt + n] = v * mf + bout[n];
    }
}

// ---------- kernel 4: CRF LLH (one wave per batch) ----------
__global__ void crf_kernel(const int* __restrict__ tags, const int* __restrict__ mask,
                           const float* __restrict__ emis, const float* __restrict__ trans,
                           const float* __restrict__ startt, const float* __restrict__ endt,
                           float* __restrict__ out) {
    int b = blockIdx.x;
    int lane = threadIdx.x;

    float part = 0.f;
    int mc = 0;
    for (int t = lane; t < Tn; t += 64) {
        int mv = mask[t * Bn + b];
        mc += mv;
        if (t >= 1) {
            int tp = tags[(t - 1) * Bn + b], tc = tags[t * Bn + b];
            part += (trans[tp * Nt + tc] + emis[(t * Bn + b) * Nt + tc]) * (float)mv;
        }
    }
    #pragma unroll
    for (int off = 32; off; off >>= 1) {
        part += __shfl_down(part, off);
        mc += __shfl_down(mc, off);
    }
    float num = 0.f;
    if (lane == 0) {
        int t0g = tags[b];
        num = startt[t0g] + emis[b * Nt + t0g] + part;
        int last = mc - 1;
        num += endt[tags[last * Bn + b]];
    }

    if (lane < Nt) {
        int j = lane;
        float tr[6];
        #pragma unroll
        for (int i = 0; i < Nt; ++i) tr[i] = trans[i * Nt + j];
        float score = startt[j] + emis[b * Nt + j];
        float e_nx = emis[(Bn + b) * Nt + j];
        int   m_nx = mask[Bn + b];
        for (int t = 1; t < Tn; ++t) {
            float e = e_nx;
            int mv = m_nx;
            if (t + 1 < Tn) {
                e_nx = emis[((t + 1) * Bn + b) * Nt + j];
                m_nx = mask[(t + 1) * Bn + b];
            }
            float v[6];
            float mx = -1e30f;
            #pragma unroll
            for (int i = 0; i < Nt; ++i) { v[i] = __shfl(score, i) + tr[i]; mx = fmaxf(mx, v[i]); }
            float sm = 0.f;
            #pragma unroll
            for (int i = 0; i < Nt; ++i) sm += __expf(v[i] - mx);
            float nxtv = mx + __logf(sm) + e;
            score = mv > 0 ? nxtv : score;
        }
        float fvv = score + endt[j];
        float m2 = fvv;
        #pragma unroll
        for (int i = 0; i < Nt; ++i) m2 = fmaxf(m2, __shfl(fvv, i));
        float s2 = 0.f;
        #pragma unroll
        for (int i = 0; i < Nt; ++i) s2 += __expf(__shfl(fvv, i) - m2);
        if (lane == 0) {
            float denom = m2 + __logf(s2);
            atomicAdd(out, num - denom);
        }
    }
}

extern "C" void kernel_launch(void* const* d_in, const int* in_sizes, int n_in,
                              void* d_out, int out_size, void* d_ws, size_t ws_size,
                              hipStream_t stream) {
    (void)in_sizes; (void)n_in; (void)out_size; (void)ws_size;
    const int*   sent  = (const int*)d_in[0];
    const int*   tags  = (const int*)d_in[1];
    const int*   mask  = (const int*)d_in[2];
    const float* h0    = (const float*)d_in[3];
    const float* c0    = (const float*)d_in[4];
    const float* embed = (const float*)d_in[5];
    const float* Wihf  = (const float*)d_in[6];
    const float* Whhf  = (const float*)d_in[7];
    const float* bf_   = (const float*)d_in[8];
    const float* Wihb  = (const float*)d_in[9];
    const float* Whhb  = (const float*)d_in[10];
    const float* bb_   = (const float*)d_in[11];
    const float* Wout  = (const float*)d_in[12];
    const float* bout  = (const float*)d_in[13];
    const float* trans = (const float*)d_in[14];
    const float* stt   = (const float*)d_in[15];
    const float* ent   = (const float*)d_in[16];
    float* out = (float*)d_out;
    char* ws = (char*)d_ws;

    ushort_t* x_bf   = (ushort_t*)(ws + OFF_XBF);
    ushort_t* Wih_bf = (ushort_t*)(ws + OFF_WIH);
    ushort_t* Whh_bf = (ushort_t*)(ws + OFF_WHH);
    ushort_t* hbuf   = (ushort_t*)(ws + OFF_HBUF);
    float*    emis   = (float*)(ws + OFF_EMIS);

    // prep threads: 524288+262144+1048576+32768+1048576+1 = 2,916,353
    prep_kernel<<<11393, 256, 0, stream>>>(sent, embed, Wihf, Whhf, Wihb, Whhb,
                                           h0, out, x_bf, Wih_bf, Whh_bf, hbuf);
    lstm_kernel<<<128, 256, 0, stream>>>(x_bf, Wih_bf, Whh_bf, bf_, bb_, c0,
                                         mask, hbuf);
    emis_kernel<<<4096, 256, 0, stream>>>(hbuf, mask, Wout, bout, emis);
    crf_kernel<<<64, 64, 0, stream>>>(tags, mask, emis, trans, stt, ent, out);
}

// Round 9
// 823.732 us; speedup vs baseline: 1.6561x; 1.1998x over previous
//
#include <hip/hip_runtime.h>

typedef unsigned short ushort_t;
typedef unsigned int uint_t;
typedef __attribute__((ext_vector_type(8))) short short8;
typedef __attribute__((ext_vector_type(4))) float f32x4;
typedef __attribute__((ext_vector_type(4))) uint_t uint4a;
typedef __attribute__((ext_vector_type(2))) uint_t uint2a;

#define Tn 256
#define Bn 64
#define Hn 512
#define En 256
#define G4 2048
#define Nt 6

// bf16 NaN sentinel: f2bf of any finite float can yield at most 0x7F80 (inf);
// 0x7FC0 (quiet NaN) is unreachable => safe "not yet written" marker.
#define SENT 0x7FC07FC0u

// ---------- helpers ----------
__device__ inline ushort_t f2bf(float f) {
    uint_t u = __float_as_uint(f);
    uint_t r = u + 0x7FFFu + ((u >> 16) & 1u);
    return (ushort_t)(r >> 16);
}
__device__ inline float bf2f(ushort_t h) { return __uint_as_float(((uint_t)h) << 16); }
__device__ inline float sigm(float x) { return 1.f / (1.f + __expf(-x)); }
__device__ inline float tanh_(float x) { return 2.f / (1.f + __expf(-2.f * x)) - 1.f; }

// All steady-loop VMEM is inline asm: the wave's vmcnt ledger is fully ours
// (no hidden compiler vmcnt(0) drains). sc1 = device scope (IF$ coherence
// point); plain = L2-cached (x, mask). !! asm loads are invisible to the
// compiler's waitcnt pass: wait + sched_barrier(0) before ANY consumer,
// including register-only sentinel compares.
__device__ inline uint4a gload16_sc1(const void* p) {
    uint4a r;
    asm volatile("global_load_dwordx4 %0, %1, off sc1" : "=v"(r) : "v"(p) : "memory");
    return r;
}
__device__ inline uint4a gload16_pl(const void* p) {
    uint4a r;
    asm volatile("global_load_dwordx4 %0, %1, off" : "=v"(r) : "v"(p) : "memory");
    return r;
}
__device__ inline int gload4_pl(const void* p) {
    int r;
    asm volatile("global_load_dword %0, %1, off" : "=v"(r) : "v"(p) : "memory");
    return r;
}
__device__ inline void gstore4_sc1(void* p, uint_t v) {
    asm volatile("global_store_dword %0, %1, off sc1" :: "v"(p), "v"(v) : "memory");
}
__device__ inline void vm_drain() { asm volatile("s_waitcnt vmcnt(0)" ::: "memory"); }

// ---------- ws layout (bytes) ----------
// hbuf: [dir][257 slots][bq(4)][slice(16)][b(16)][j(32)] bf16.
// P=16/Bp=16 decomposition: 8 groups (dir x batch-quarter) x 16 slice-WGs.
// Producer (dir,bq,slice) writes one contiguous 1KB block per step (full
// 128B lines, single owner). Consumer reads only its 16KB bq-pane (16
// producers) => broadcast traffic + straggler pool HALVED vs P=32 at
// constant per-WG compute. Slot s = h after s steps (slot 0 = h0).
// Write-once => data-is-the-flag synchronization.
#define OFF_XBF    0u               // 16384*256 bf16        = 8,388,608
#define OFF_WIH    8388608u         // 2*2048*256 bf16       = 2,097,152
#define OFF_WHH    10485760u        // 2*2048*512 bf16       = 4,194,304
#define OFF_HBUF   14680064u        // 2*257*64*512 bf16     = 33,685,504 (end 48,365,568)
#define OFF_EMIS   8388608u         // overlays WIH (dead after lstm; prep rewrites each call)

#define SLOT_U     32768u           // ushorts per slot (4 bq * 8192)
#define BQ_U       8192u            // ushorts per bq pane (16 slices * 512)
#define DIR_U      8421376u         // ushorts per dir (257*32768)

// ---------- kernel 1: prep ----------
__global__ void prep_kernel(const int* __restrict__ sent, const float* __restrict__ embed,
                            const float* __restrict__ Wihf, const float* __restrict__ Whhf,
                            const float* __restrict__ Wihb, const float* __restrict__ Whhb,
                            const float* __restrict__ h0, float* __restrict__ out,
                            ushort_t* __restrict__ x_bf, ushort_t* __restrict__ Wih_bf,
                            ushort_t* __restrict__ Whh_bf, ushort_t* __restrict__ hbuf) {
    long i = (long)blockIdx.x * 256 + threadIdx.x;
    const long nA = 524288, nB = 262144, nC = 1048576, nD = 32768, nE = 1048576;
    if (i < nA) {  // Whh cast: [dir][2048][512], 4 elems
        long e4 = i << 2;
        long d = e4 >> 20, r = e4 & 1048575;
        const float* W = d ? Whhb : Whhf;
        float4 v = *(const float4*)(W + r);
        uint2a pv;
        pv.x = (uint_t)f2bf(v.x) | ((uint_t)f2bf(v.y) << 16);
        pv.y = (uint_t)f2bf(v.z) | ((uint_t)f2bf(v.w) << 16);
        *(uint2a*)(Whh_bf + e4) = pv;
        return;
    }
    i -= nA;
    if (i < nB) {  // Wih cast: [dir][2048][256], 4 elems
        long e4 = i << 2;
        long d = e4 >> 19, r = e4 & 524287;
        const float* W = d ? Wihb : Wihf;
        float4 v = *(const float4*)(W + r);
        uint2a pv;
        pv.x = (uint_t)f2bf(v.x) | ((uint_t)f2bf(v.y) << 16);
        pv.y = (uint_t)f2bf(v.z) | ((uint_t)f2bf(v.w) << 16);
        *(uint2a*)(Wih_bf + (d << 19) + r) = pv;
        return;
    }
    i -= nB;
    if (i < nC) {  // x gather: row = t*B+b, 4 elems within one embed row
        long e4 = i << 2;
        long row = e4 >> 8, e = e4 & 255;
        int tok = sent[row];
        float4 v = *(const float4*)(embed + (size_t)tok * 256 + e);
        uint2a pv;
        pv.x = (uint_t)f2bf(v.x) | ((uint_t)f2bf(v.y) << 16);
        pv.y = (uint_t)f2bf(v.z) | ((uint_t)f2bf(v.w) << 16);
        *(uint2a*)(x_bf + e4) = pv;
        return;
    }
    i -= nC;
    if (i < nD) {  // h0 -> hbuf[dir][slot0] in [bq][slice][b][j] layout, sc1.
        long dir = i >> 14, rem = i & 16383;
        long b = rem >> 8, jw = rem & 255;
        long col = jw * 2;
        const float* hp = h0 + (size_t)dir * Bn * Hn + (size_t)b * Hn + col;
        gstore4_sc1(hbuf + (size_t)dir * DIR_U + (b >> 4) * BQ_U
                         + (col >> 5) * 512 + (b & 15) * 32 + (col & 31),
                    (uint_t)f2bf(hp[0]) | ((uint_t)f2bf(hp[1]) << 16));
        return;
    }
    i -= nD;
    if (i < nE) {  // sentinel fill: slots 1..256 both dirs, 32B/thread
                   // (layout-agnostic uniform fill).
        long dir = i >> 19, rem = i & 524287;
        ushort_t* p = hbuf + (size_t)dir * DIR_U + SLOT_U + (size_t)rem * 16;
        uint4a s; s.x = SENT; s.y = SENT; s.z = SENT; s.w = SENT;
        *(uint4a*)p = s;
        *(uint4a*)(p + 8) = s;
        return;
    }
    if (i == nE) { out[0] = 0.f; }
}

// ---------- kernel 2: persistent fused BiLSTM (P=16/Bp=16) ----------
// 128 WGs: dir(2) x bq(4) x slice(16). 256 threads. Each WG: 128 gate rows
// (4 types x 32 j) x 16 batches. Data-is-the-flag sentinel protocol,
// single vm_drain per iteration:
//  A: issue [x(t+1) x2, mask(t+1), h(slot s, own bq pane) x4]  (inline asm)
//  B: x-MFMAs: 8 ksteps x 2 N-tiles (load flight)
//  C: ONE drain; per-chunk validate; PARTIAL retry; stage h_s + x_s[nxt]
//  D: h-MFMAs: 16 ksteps x 2 N-tiles; gates -> LDS (stride 17)
//  E: cell update; ONE contiguous 1KB sc1 h-store block
__global__ void __launch_bounds__(256, 1) lstm_kernel(
    const ushort_t* __restrict__ x_bf, const ushort_t* __restrict__ Wih_bf,
    const ushort_t* __restrict__ Whh_bf, const float* __restrict__ biasf,
    const float* __restrict__ biasb, const float* __restrict__ c0,
    const int* __restrict__ mask, ushort_t* __restrict__ hbuf) {

    __shared__ __align__(16) ushort_t x_s[2][16 * 264];   // 16,896 B
    __shared__ __align__(16) ushort_t h_s[16 * 520];      // 16,640 B
    __shared__ __align__(16) float gates_s[128 * 17];     //  8,704 B
    __shared__ ushort_t pad_s[20480];                     // 40,960 B -> >80KB: 1 WG/CU

    const int tid = threadIdx.x;
    const int wid = blockIdx.x;
    const int dir = wid >> 6;
    const int bq  = (wid >> 4) & 3;
    const int sl  = wid & 15;
    const int j0  = sl * 32;
    if (tid == 0) pad_s[0] = 0;   // keep pad_s allocated

    const int lane = tid & 63;
    const int wv = tid >> 6;            // wave = gate type (i,f,g,o)
    const int qo = (lane >> 4) * 8;     // k-chunk offset in fragment
    const int ml = lane & 15;

    // persistent B fragments: 2 N-tiles x (8 x-ksteps + 16 h-ksteps).
    // tile n rows = wv*512 + j0 + n*16 + ml. ~192 VGPR; 1 WG/CU => 512 budget.
    short8 bxf0[8], bxf1[8], bhf0[16], bhf1[16];
    {
        const int r0 = wv * 512 + j0 + ml;
        const int r1 = r0 + 16;
        const ushort_t* w0 = Wih_bf + (size_t)dir * G4 * En + (size_t)r0 * En + qo;
        const ushort_t* w1 = Wih_bf + (size_t)dir * G4 * En + (size_t)r1 * En + qo;
        #pragma unroll
        for (int ks = 0; ks < 8; ++ks) {
            bxf0[ks] = *(const short8*)(w0 + ks * 32);
            bxf1[ks] = *(const short8*)(w1 + ks * 32);
        }
        const ushort_t* v0 = Whh_bf + (size_t)dir * G4 * Hn + (size_t)r0 * Hn + qo;
        const ushort_t* v1 = Whh_bf + (size_t)dir * G4 * Hn + (size_t)r1 * Hn + qo;
        #pragma unroll
        for (int ks = 0; ks < 16; ++ks) {
            bhf0[ks] = *(const short8*)(v0 + ks * 32);
            bhf1[ks] = *(const short8*)(v1 + ks * 32);
        }
    }
    const float* bias = dir ? biasb : biasf;
    const float bv0 = bias[wv * 512 + j0 + ml];
    const float bv1 = bias[wv * 512 + j0 + 16 + ml];

    // update mapping: thread -> (batch ub, 2 consecutive j) => one 4B store
    const int ub = tid >> 4;            // batch within pane 0..15
    const int uj = (tid & 15) * 2;      // j 0..30
    const int bg = bq * 16 + ub;        // global batch
    float creg[2];
    #pragma unroll
    for (int r = 0; r < 2; ++r)
        creg[r] = c0[(size_t)dir * Bn * Hn + (size_t)bg * Hn + j0 + uj + r];

    const ushort_t* xbase = x_bf + (size_t)bq * 16 * En;   // + t*Bn*En per step
    const size_t paneoff = (size_t)dir * DIR_U + (size_t)bq * BQ_U;

    // prologue (compiler loads, auto-drained): x[t0] -> x_s[0] (8KB); mv(t0)
    {
        const int t0 = dir ? (Tn - 1) : 0;
        const uint4* g4 = (const uint4*)(xbase + (size_t)t0 * Bn * En);
        uint4 xp[2];
        #pragma unroll
        for (int k = 0; k < 2; ++k) xp[k] = g4[tid + k * 256];
        #pragma unroll
        for (int k = 0; k < 2; ++k) {
            int c16 = tid + k * 256;
            *(uint4*)&x_s[0][(c16 >> 5) * 264 + (c16 & 31) * 8] = xp[k];
        }
    }
    int mv = mask[(dir ? (Tn - 1) : 0) * Bn + bg];
    __syncthreads();

    for (int s = 0; s < Tn; ++s) {
        const int cur = s & 1, nxt = cur ^ 1;

        // A: asm bundle — x(t of iter s+1) x2, mask(same), h(slot s) x4
        const int sn = (s + 1 < Tn) ? s + 1 : Tn - 1;
        const int tn = dir ? (Tn - 1 - sn) : sn;
        uint4a xreg[2];
        {
            const ushort_t* g = xbase + (size_t)tn * Bn * En;
            #pragma unroll
            for (int k = 0; k < 2; ++k)
                xreg[k] = gload16_pl(g + (size_t)(tid + k * 256) * 8);
        }
        int mnx = gload4_pl(&mask[tn * Bn + bg]);
        const ushort_t* hp0 = hbuf + paneoff + (size_t)s * SLOT_U;
        uint4a hreg[4];
        #pragma unroll
        for (int k = 0; k < 4; ++k)
            hreg[k] = gload16_sc1(hp0 + (size_t)(tid + k * 256) * 8);

        // B: x-part MFMAs, 8 ksteps x 2 N-tiles (load flight)
        f32x4 acc0, acc1;
        #pragma unroll
        for (int r = 0; r < 4; ++r) { acc0[r] = bv0; acc1[r] = bv1; }
        const ushort_t* xr0 = &x_s[cur][ml * 264 + qo];
        #pragma unroll
        for (int ks = 0; ks < 8; ++ks) {
            short8 a = *(const short8*)(xr0 + ks * 32);
            acc0 = __builtin_amdgcn_mfma_f32_16x16x32_bf16(a, bxf0[ks], acc0, 0, 0, 0);
            acc1 = __builtin_amdgcn_mfma_f32_16x16x32_bf16(a, bxf1[ks], acc1, 0, 0, 0);
        }

        // C: the ONE drain; per-chunk validate; PARTIAL retry.
        //    Bounded guard: wrong-answer-not-hang on any protocol bug.
        vm_drain();
        __builtin_amdgcn_sched_barrier(0);
        {
            uint_t okm = 0;
            #pragma unroll
            for (int k = 0; k < 4; ++k) {
                bool ok = true;
                #pragma unroll
                for (int w = 0; w < 4; ++w) ok &= (hreg[k][w] != SENT);
                okm |= (ok ? 1u : 0u) << k;
            }
            int guard = 65536;
            while (okm != 15u && --guard) {
                __builtin_amdgcn_s_sleep(1);
                #pragma unroll
                for (int k = 0; k < 4; ++k)
                    if (!((okm >> k) & 1))
                        hreg[k] = gload16_sc1(hp0 + (size_t)(tid + k * 256) * 8);
                vm_drain();
                __builtin_amdgcn_sched_barrier(0);
                #pragma unroll
                for (int k = 0; k < 4; ++k) {
                    if (!((okm >> k) & 1)) {
                        bool ok = true;
                        #pragma unroll
                        for (int w = 0; w < 4; ++w) ok &= (hreg[k][w] != SENT);
                        okm |= (ok ? 1u : 0u) << k;
                    }
                }
            }
        }
        // stage h into h_s[b][col]: chunk c16 -> slice=c16>>6, b=(c16>>2)&15,
        // jc=c16&3; col = slice*32 + jc*8 (pane is [slice][b][j])
        #pragma unroll
        for (int k = 0; k < 4; ++k) {
            int c16 = tid + k * 256;
            int slc = c16 >> 6, b = (c16 >> 2) & 15, jc = c16 & 3;
            *(uint4a*)&h_s[b * 520 + slc * 32 + jc * 8] = hreg[k];
        }
        #pragma unroll
        for (int k = 0; k < 2; ++k) {
            int c16 = tid + k * 256;
            *(uint4a*)&x_s[nxt][(c16 >> 5) * 264 + (c16 & 31) * 8] = xreg[k];
        }
        __syncthreads();

        // D: h-part MFMAs, 16 ksteps x 2 N-tiles; gates -> LDS (stride 17)
        {
            const ushort_t* hr0 = &h_s[ml * 520 + qo];
            #pragma unroll
            for (int ks = 0; ks < 16; ++ks) {
                short8 a = *(const short8*)(hr0 + ks * 32);
                acc0 = __builtin_amdgcn_mfma_f32_16x16x32_bf16(a, bhf0[ks], acc0, 0, 0, 0);
                acc1 = __builtin_amdgcn_mfma_f32_16x16x32_bf16(a, bhf1[ks], acc1, 0, 0, 0);
            }
            int nl0 = wv * 32 + ml;        // local gate row, tile 0
            int br = (lane >> 4) * 4;      // batch base
            #pragma unroll
            for (int r = 0; r < 4; ++r) {
                gates_s[nl0 * 17 + br + r]        = acc0[r];
                gates_s[(nl0 + 16) * 17 + br + r] = acc1[r];
            }
        }
        __syncthreads();

        // E: cell update; contiguous 1KB sc1 h-store (full-line single-owner)
        {
            ushort_t hu[2];
            #pragma unroll
            for (int r = 0; r < 2; ++r) {
                int j = uj + r;
                float iv  = gates_s[j * 17 + ub];              // type 0 row j
                float fvv = gates_s[(32 + j) * 17 + ub];       // type 1
                float gv  = gates_s[(64 + j) * 17 + ub];       // type 2
                float ov  = gates_s[(96 + j) * 17 + ub];       // type 3
                float cn = sigm(fvv) * creg[r] + sigm(iv) * tanh_(gv);
                float hn = sigm(ov) * tanh_(cn);
                float hp = bf2f(h_s[ub * 520 + j0 + j]);
                float h2;
                if (mv) { creg[r] = cn; h2 = hn; }
                else    { h2 = hp; }
                hu[r] = f2bf(h2);
            }
            gstore4_sc1(hbuf + paneoff + (size_t)(s + 1) * SLOT_U
                             + (size_t)sl * 512 + (size_t)ub * 32 + uj,
                        (uint_t)hu[0] | ((uint_t)hu[1] << 16));
        }
        mv = mnx;
        // protect h_s (read in E) / x_s[nxt] / gates_s for next iteration
        __syncthreads();
    }
}

// ---------- kernel 3: emission projection (wave per row) ----------
// h_masked[t] = mask(t) ? hbuf[dir0][t+1] / hbuf[dir1][256-t] : 0.
// Pane layout [bq][slice][b][j]: lane covers 16 cols = half a slice run.
__global__ void emis_kernel(const ushort_t* __restrict__ hbuf, const int* __restrict__ mask,
                            const float* __restrict__ Wout, const float* __restrict__ bout,
                            float* __restrict__ emis) {
    int row = blockIdx.x * 4 + (threadIdx.x >> 6);   // t*64 + b
    int lane = threadIdx.x & 63;
    int t = row >> 6, b = row & 63;
    float mf = mask[row] ? 1.f : 0.f;
    size_t slot = (lane < 32) ? (size_t)(t + 1) * SLOT_U
                              : (size_t)DIR_U + (size_t)(Tn - t) * SLOT_U;
    int l5 = lane & 31;
    const ushort_t* hr = hbuf + slot + (size_t)(b >> 4) * BQ_U
                       + (size_t)(l5 >> 1) * 512 + (size_t)(b & 15) * 32
                       + (size_t)(l5 & 1) * 16;
    short8 h0v = *(const short8*)(hr);
    short8 h1v = *(const short8*)(hr + 8);
    float hv[16];
    #pragma unroll
    for (int j = 0; j < 8; ++j) {
        hv[j]     = bf2f((ushort_t)h0v[j]);
        hv[j + 8] = bf2f((ushort_t)h1v[j]);
    }
    float acc[6];
    #pragma unroll
    for (int n = 0; n < Nt; ++n) {
        const float* w = Wout + n * 1024 + lane * 16;   // lane*16 == concat index
        float a = 0.f;
        #pragma unroll
        for (int j = 0; j < 16; ++j) a += hv[j] * w[j];
        acc[n] = a;
    }
    #pragma unroll
    for (int n = 0; n < Nt; ++n) {
        float v = acc[n];
        #pragma unroll
        for (int off = 32; off; off >>= 1) v += __shfl_down(v, off);
        if (lane == 0) emis[row * Nt + n] = v * mf + bout[n];
    }
}

// ---------- kernel 4: CRF LLH (one wave per batch) ----------
__global__ void crf_kernel(const int* __restrict__ tags, const int* __restrict__ mask,
                           const float* __restrict__ emis, const float* __restrict__ trans,
                           const float* __restrict__ startt, const float* __restrict__ endt,
                           float* __restrict__ out) {
    int b = blockIdx.x;
    int lane = threadIdx.x;

    float part = 0.f;
    int mc = 0;
    for (int t = lane; t < Tn; t += 64) {
        int mv = mask[t * Bn + b];
        mc += mv;
        if (t >= 1) {
            int tp = tags[(t - 1) * Bn + b], tc = tags[t * Bn + b];
            part += (trans[tp * Nt + tc] + emis[(t * Bn + b) * Nt + tc]) * (float)mv;
        }
    }
    #pragma unroll
    for (int off = 32; off; off >>= 1) {
        part += __shfl_down(part, off);
        mc += __shfl_down(mc, off);
    }
    float num = 0.f;
    if (lane == 0) {
        int t0g = tags[b];
        num = startt[t0g] + emis[b * Nt + t0g] + part;
        int last = mc - 1;
        num += endt[tags[last * Bn + b]];
    }

    if (lane < Nt) {
        int j = lane;
        float tr[6];
        #pragma unroll
        for (int i = 0; i < Nt; ++i) tr[i] = trans[i * Nt + j];
        float score = startt[j] + emis[b * Nt + j];
        float e_nx = emis[(Bn + b) * Nt + j];
        int   m_nx = mask[Bn + b];
        for (int t = 1; t < Tn; ++t) {
            float e = e_nx;
            int mv = m_nx;
            if (t + 1 < Tn) {
                e_nx = emis[((t + 1) * Bn + b) * Nt + j];
                m_nx = mask[(t + 1) * Bn + b];
            }
            float v[6];
            float mx = -1e30f;
            #pragma unroll
            for (int i = 0; i < Nt; ++i) { v[i] = __shfl(score, i) + tr[i]; mx = fmaxf(mx, v[i]); }
            float sm = 0.f;
            #pragma unroll
            for (int i = 0; i < Nt; ++i) sm += __expf(v[i] - mx);
            float nxtv = mx + __logf(sm) + e;
            score = mv > 0 ? nxtv : score;
        }
        float fvv = score + endt[j];
        float m2 = fvv;
        #pragma unroll
        for (int i = 0; i < Nt; ++i) m2 = fmaxf(m2, __shfl(fvv, i));
        float s2 = 0.f;
        #pragma unroll
        for (int i = 0; i < Nt; ++i) s2 += __expf(__shfl(fvv, i) - m2);
        if (lane == 0) {
            float denom = m2 + __logf(s2);
            atomicAdd(out, num - denom);
        }
    }
}

extern "C" void kernel_launch(void* const* d_in, const int* in_sizes, int n_in,
                              void* d_out, int out_size, void* d_ws, size_t ws_size,
                              hipStream_t stream) {
    (void)in_sizes; (void)n_in; (void)out_size; (void)ws_size;
    const int*   sent  = (const int*)d_in[0];
    const int*   tags  = (const int*)d_in[1];
    const int*   mask  = (const int*)d_in[2];
    const float* h0    = (const float*)d_in[3];
    const float* c0    = (const float*)d_in[4];
    const float* embed = (const float*)d_in[5];
    const float* Wihf  = (const float*)d_in[6];
    const float* Whhf  = (const float*)d_in[7];
    const float* bf_   = (const float*)d_in[8];
    const float* Wihb  = (const float*)d_in[9];
    const float* Whhb  = (const float*)d_in[10];
    const float* bb_   = (const float*)d_in[11];
    const float* Wout  = (const float*)d_in[12];
    const float* bout  = (const float*)d_in[13];
    const float* trans = (const float*)d_in[14];
    const float* stt   = (const float*)d_in[15];
    const float* ent   = (const float*)d_in[16];
    float* out = (float*)d_out;
    char* ws = (char*)d_ws;

    ushort_t* x_bf   = (ushort_t*)(ws + OFF_XBF);
    ushort_t* Wih_bf = (ushort_t*)(ws + OFF_WIH);
    ushort_t* Whh_bf = (ushort_t*)(ws + OFF_WHH);
    ushort_t* hbuf   = (ushort_t*)(ws + OFF_HBUF);
    float*    emis   = (float*)(ws + OFF_EMIS);

    // prep threads: 524288+262144+1048576+32768+1048576+1 = 2,916,353
    prep_kernel<<<11393, 256, 0, stream>>>(sent, embed, Wihf, Whhf, Wihb, Whhb,
                                           h0, out, x_bf, Wih_bf, Whh_bf, hbuf);
    lstm_kernel<<<128, 256, 0, stream>>>(x_bf, Wih_bf, Whh_bf, bf_, bb_, c0,
                                         mask, hbuf);
    emis_kernel<<<4096, 256, 0, stream>>>(hbuf, mask, Wout, bout, emis);
    crf_kernel<<<64, 64, 0, stream>>>(tags, mask, emis, trans, stt, ent, out);
}